// Round 11
// baseline (1173.717 us; speedup 1.0000x reference)
//
#include <hip/hip_runtime.h>
#include <hip/hip_cooperative_groups.h>

namespace cg = cooperative_groups;

#define LOG2E 1.4426950408889634f
#define TWO_LOG2E 2.8853900817779268f

#if __has_builtin(__builtin_amdgcn_exp2f)
__device__ __forceinline__ float fexp2(float x){ return __builtin_amdgcn_exp2f(x); }
#else
__device__ __forceinline__ float fexp2(float x){ return exp2f(x); }
#endif
#if __has_builtin(__builtin_amdgcn_rcpf)
__device__ __forceinline__ float frcp(float x){ return __builtin_amdgcn_rcpf(x); }
#else
__device__ __forceinline__ float frcp(float x){ return 1.0f/(x); }
#endif

// DPP cross-lane move (full-rate VALU, no LDS pipe)
template<int CTRL>
__device__ __forceinline__ float dpp_f(float x) {
    return __int_as_float(__builtin_amdgcn_update_dpp(0, __float_as_int(x), CTRL, 0xF, 0xF, true));
}
#define DPP_XOR1  0xB1   // quad_perm(1,0,3,2)
#define DPP_XOR2  0x4E   // quad_perm(2,3,0,1)
#define DPP_BC0   0x00   // quad bcast lane0
#define DPP_BC1   0x55
#define DPP_BC2   0xAA
#define DPP_BC3   0xFF

// ---- shared-memory plan (floats), phases are grid.sync-separated ----------
// gemm : Xs = smem[0..2112), Ws = smem[2112..4224)
// lstm : hbuf = smem[0..256)
// score: half h at smem + h*6736: As[0..4224) Bs[4224..6336) W2s[6336..6464) ps[6464..6736)
// softmax: rbuf = smem[0..8), rbuf2 = smem[8..16)
#define SM_FLOATS 13472

// ---------------- 64x64 GEMM tile, 512 threads ------------------------------
// each thread: rows {2ty,2ty+1} x cols {4tx..4tx+3}; staging: 1 float4/thread
// per 32-K panel. L0 variant gathers X rows from the embedding tables.
template<bool L0>
__device__ __forceinline__ void gemm_tile(
    float* __restrict__ Xs, float* __restrict__ Ws, int tid,
    const float* __restrict__ X, int ldx,
    const float* __restrict__ W, int ldw, int woff,
    const float* __restrict__ bb1, const float* __restrict__ bb2,
    float* __restrict__ C, int n0, int r0, int K, float scale,
    const int* __restrict__ wid, const int* __restrict__ tgi,
    const float* __restrict__ wemb, const float* __restrict__ temb)
{
    int tx = tid & 15, ty = tid >> 4;     // ty 0..31
    int row = tid >> 3, c4 = tid & 7;     // 64 rows x 8 float4
    float acc[2][4] = {};
    for (int k0 = 0; k0 < K; k0 += 32) {
        int k = k0 + c4*4;
        float4 vx, vw;
        if (L0) {
            int rg = n0 + row;
            vx = (k < 100) ? *(const float4*)(wemb + wid[rg]*100 + k)
                           : *(const float4*)(temb + tgi[rg]*28 + (k-100));
            vw = *(const float4*)(W + (r0+row)*128 + k);
        } else {
            vx = *(const float4*)(X + (n0+row)*ldx + k);
            vw = *(const float4*)(W + (r0+row)*ldw + woff + k);
        }
        Xs[row*33 + c4*4+0]=vx.x; Xs[row*33 + c4*4+1]=vx.y; Xs[row*33 + c4*4+2]=vx.z; Xs[row*33 + c4*4+3]=vx.w;
        Ws[row*33 + c4*4+0]=vw.x; Ws[row*33 + c4*4+1]=vw.y; Ws[row*33 + c4*4+2]=vw.z; Ws[row*33 + c4*4+3]=vw.w;
        __syncthreads();
        #pragma unroll 8
        for (int kk = 0; kk < 32; ++kk) {
            float a0 = Xs[(2*ty)*33 + kk];
            float a1 = Xs[(2*ty+1)*33 + kk];
            float bv[4];
            #pragma unroll
            for (int jj = 0; jj < 4; ++jj) bv[jj] = Ws[(4*tx+jj)*33 + kk];
            #pragma unroll
            for (int jj = 0; jj < 4; ++jj) {
                acc[0][jj] = fmaf(a0, bv[jj], acc[0][jj]);
                acc[1][jj] = fmaf(a1, bv[jj], acc[1][jj]);
            }
        }
        __syncthreads();
    }
    #pragma unroll
    for (int i = 0; i < 2; ++i)
        #pragma unroll
        for (int jj = 0; jj < 4; ++jj) {
            int r = r0 + 4*tx + jj;
            float v = acc[i][jj];
            if (bb1) v += bb1[r];
            if (bb2) v += bb2[r];
            C[(n0 + 2*ty + i)*512 + r] = v*scale;
        }
}

// ---------------- LSTM phase: R6-exact (512 thr, R=4 x C=32, AGPR weights) --
__device__ __forceinline__ void lstm_body(
    float* hbuf, int tid, int dir, int layer,
    const float* __restrict__ preD, const float* __restrict__ Whh,
    const float* __restrict__ h0, const float* __restrict__ c0,
    float* hout)
{
    const int sub = tid & 3;        // col slice 0..3
    const int j   = tid >> 2;       // cell 0..127
    const int q   = sub;

    // R6-verified conflict-free chunk schedule
    int cidx[8];
    #pragma unroll
    for (int k = 0; k < 8; ++k) cidx[k] = (sub << 3) + ((k + 2*sub) & 7);

    float w[4][32];                 // AGPR-resident (scalar v_fmac sources AGPR)
    #pragma unroll
    for (int r = 0; r < 4; ++r) {
        const float* wr = Whh + ((r << 7) + j)*128;
        #pragma unroll
        for (int k = 0; k < 8; ++k) {
            float4 v = *(const float4*)(wr + 4*cidx[k]);
            w[r][4*k+0]=v.x; w[r][4*k+1]=v.y; w[r][4*k+2]=v.z; w[r][4*k+3]=v.w;
        }
    }

    const float* h0d = h0 + (2*layer + dir)*128;
    const float* c0d = c0 + (2*layer + dir)*128;
    float c = c0d[j];
    if (tid < 128) hbuf[tid] = h0d[tid];

    const float sc = (q == 2) ? -TWO_LOG2E : -LOG2E;
    const int prow = (q << 7) + j;
    const int t0 = dir ? 511 : 0;
    const int dt = dir ? -1 : 1;

    float pcur = preD[t0*512 + prow];
    __syncthreads();

    #pragma unroll 2
    for (int s = 0; s < 512; ++s) {
        const int t  = t0 + dt*s;
        const int tn = (s < 511) ? (t + dt) : t;
        float pnext = preD[tn*512 + prow];

        const int p = s & 1;
        const float4* h4 = (const float4*)(hbuf + p*128);
        float4 hv[8];
        #pragma unroll
        for (int k = 0; k < 8; ++k) hv[k] = h4[cidx[k]];

        float acc[4] = {0.f, 0.f, 0.f, 0.f};
        #pragma unroll
        for (int k = 0; k < 8; ++k) {
            #pragma unroll
            for (int r = 0; r < 4; ++r) {
                acc[r] = fmaf(hv[k].x, w[r][4*k+0], acc[r]);
                acc[r] = fmaf(hv[k].y, w[r][4*k+1], acc[r]);
                acc[r] = fmaf(hv[k].z, w[r][4*k+2], acc[r]);
                acc[r] = fmaf(hv[k].w, w[r][4*k+3], acc[r]);
            }
        }

        #pragma unroll
        for (int r = 0; r < 4; ++r) {
            acc[r] += dpp_f<DPP_XOR1>(acc[r]);
            acc[r] += dpp_f<DPP_XOR2>(acc[r]);
        }

        float a01 = (q & 1) ? acc[1] : acc[0];
        float a23 = (q & 1) ? acc[3] : acc[2];
        float xg  = (((q & 2) ? a23 : a01) + pcur) * sc;
        float sv  = frcp(1.f + fexp2(xg));

        float vi = dpp_f<DPP_BC0>(sv);
        float vf = dpp_f<DPP_BC1>(sv);
        float vg = dpp_f<DPP_BC2>(sv);
        float vo = dpp_f<DPP_BC3>(sv);

        float tg = fmaf(2.f, vg, -1.f);
        c = fmaf(vf, c, vi*tg);
        float th = fmaf(-2.f, frcp(1.f + fexp2(TWO_LOG2E*c)), 1.f);
        float h  = vo * th;

        if (sub == 1) hbuf[(p ^ 1)*128 + j] = h;
        if (sub == 2) hout[t*256 + dir*128 + j] = h;
        __syncthreads();
        pcur = pnext;
    }
}

// ---------------- score tile (256 threads per half-block) -------------------
__device__ __forceinline__ void score_tile(
    float* __restrict__ As, float* __restrict__ Bs,
    float* __restrict__ W2s, float* __restrict__ ps, int t,
    const float* __restrict__ Ap, const float* __restrict__ Bp,
    const float* __restrict__ W2, const float* __restrict__ b2p,
    float* S, float* csum, int m0, int n0)
{
    int tx = t & 15, ty = t >> 4;
    float acc0 = 0.f, acc1 = 0.f;
    for (int hc = 0; hc < 512; hc += 128) {
        #pragma unroll
        for (int i = 0; i < 4; ++i) {
            int idx = t + 256*i;
            int row = idx >> 5, c4 = idx & 31;
            *(float4*)&As[row*132 + c4*4] = *(const float4*)(Ap + (n0+row)*512 + hc + c4*4);
        }
        #pragma unroll
        for (int i = 0; i < 2; ++i) {
            int idx = t + 256*i;
            int row = idx >> 5, c4 = idx & 31;
            *(float4*)&Bs[row*132 + c4*4] = *(const float4*)(Bp + (m0+row)*512 + hc + c4*4);
        }
        if (t < 128) W2s[t] = W2[hc + t];
        __syncthreads();

        #pragma unroll 4
        for (int h4i = 0; h4i < 32; ++h4i) {
            float4 a0 = *(const float4*)&As[ty*132 + 4*h4i];
            float4 a1 = *(const float4*)&As[(ty+16)*132 + 4*h4i];
            float4 bv = *(const float4*)&Bs[tx*132 + 4*h4i];
            float4 w4 = *(const float4*)&W2s[4*h4i];
            float aa0[4] = {a0.x,a0.y,a0.z,a0.w};
            float aa1[4] = {a1.x,a1.y,a1.z,a1.w};
            float bb[4]  = {bv.x,bv.y,bv.z,bv.w};
            float ww[4]  = {w4.x,w4.y,w4.z,w4.w};
            #pragma unroll
            for (int qi = 0; qi < 4; ++qi) {
                float r0v = frcp(1.f + fexp2(aa0[qi] + bb[qi]));
                float r1v = frcp(1.f + fexp2(aa1[qi] + bb[qi]));
                acc0 = fmaf(ww[qi], fmaf(-2.f, r0v, 1.f), acc0);
                acc1 = fmaf(ww[qi], fmaf(-2.f, r1v, 1.f), acc1);
            }
        }
        __syncthreads();
    }

    float b2s = b2p[0];
    int gm  = m0 + tx;
    int gn0 = n0 + ty;
    int gn1 = n0 + 16 + ty;
    float v0 = acc0 + b2s; if (gn0 == gm) v0 = 0.f;
    float v1 = acc1 + b2s; if (gn1 == gm) v1 = 0.f;
    S[gn0*512 + gm] = v0;
    S[gn1*512 + gm] = v1;

    ps[ty*17 + tx] = v0 + v1;
    __syncthreads();
    if (t < 16) {
        float s = 0.f;
        #pragma unroll
        for (int k = 0; k < 16; ++k) s += ps[k*17 + t];
        atomicAdd(&csum[m0 + t], s);
    }
}

// ---------------- softmax of one row, 512 threads ---------------------------
__device__ __forceinline__ void softmax_row(
    int n, int tid, float* rbuf, float* rbuf2,
    const float* S, const float* __restrict__ csum, float* __restrict__ out)
{
    float v = S[n*512 + tid] / csum[tid];
    int lane = tid & 63, wv = tid >> 6;
    float mx = v;
    #pragma unroll
    for (int off = 32; off; off >>= 1) mx = fmaxf(mx, __shfl_xor(mx, off, 64));
    if (lane == 0) rbuf[wv] = mx;
    __syncthreads();
    mx = rbuf[0];
    #pragma unroll
    for (int k = 1; k < 8; ++k) mx = fmaxf(mx, rbuf[k]);

    float e = fexp2((v - mx)*LOG2E);
    float sm = e;
    #pragma unroll
    for (int off = 32; off; off >>= 1) sm += __shfl_xor(sm, off, 64);
    if (lane == 0) rbuf2[wv] = sm;
    __syncthreads();
    float tot = rbuf2[0];
    #pragma unroll
    for (int k = 1; k < 8; ++k) tot += rbuf2[k];

    float inv = 1.0f / tot;
    out[n*512 + tid] = e*inv;
}

// ---------------- the whole model as ONE cooperative kernel -----------------
// 256 blocks x 512 threads, 1 block/CU. Phases separated by grid.sync():
// A: pre-L0 GEMM (blocks 0-127) + csum zero (block 128)
// B: lstm layer 0 (blocks 0,1)       C: pre-L1 GEMM      D: lstm layer 1
// E: A'/B' GEMM                      F: score (2 tiles/block)  G: softmax
__global__ __launch_bounds__(512, 2) void fused(
    const int* __restrict__ wid, const int* __restrict__ tgi,
    const float* __restrict__ wemb, const float* __restrict__ temb,
    const float* __restrict__ h0, const float* __restrict__ c0,
    const float* __restrict__ Wih0f, const float* __restrict__ Whh0f,
    const float* __restrict__ bih0f, const float* __restrict__ bhh0f,
    const float* __restrict__ Wih0b, const float* __restrict__ Whh0b,
    const float* __restrict__ bih0b, const float* __restrict__ bhh0b,
    const float* __restrict__ Wih1f, const float* __restrict__ Whh1f,
    const float* __restrict__ bih1f, const float* __restrict__ bhh1f,
    const float* __restrict__ Wih1b, const float* __restrict__ Whh1b,
    const float* __restrict__ bih1b, const float* __restrict__ bhh1b,
    const float* __restrict__ W1, const float* __restrict__ b1,
    const float* __restrict__ W2, const float* __restrict__ b2,
    float* h0cat, float* h1cat,
    float* pA, float* pB,
    float* S, float* csum, float* out)
{
    __shared__ __align__(16) float smem[SM_FLOATS];
    cg::grid_group grid = cg::this_grid();
    const int b = blockIdx.x;
    const int tid = threadIdx.x;

    // ---- phase A: layer-0 pre GEMM (fused embedding gather) + csum zero ----
    if (b < 128) {
        int z = b >> 6, rem = b & 63;
        gemm_tile<true>(smem, smem + 2112, tid,
                        nullptr, 0, z ? Wih0b : Wih0f, 128, 0,
                        z ? bih0b : bih0f, z ? bhh0b : bhh0f,
                        z ? pB : pA, (rem >> 3)*64, (rem & 7)*64, 128, 1.0f,
                        wid, tgi, wemb, temb);
    } else if (b == 128) {
        csum[tid] = 0.f;
    }
    __threadfence();
    grid.sync();

    // ---- phase B: lstm layer 0 ----
    if (b < 2)
        lstm_body(smem, tid, b, 0, b ? pB : pA, b ? Whh0b : Whh0f, h0, c0, h0cat);
    __threadfence();
    grid.sync();

    // ---- phase C: layer-1 pre GEMM ----
    if (b < 128) {
        int z = b >> 6, rem = b & 63;
        gemm_tile<false>(smem, smem + 2112, tid,
                         h0cat, 256, z ? Wih1b : Wih1f, 256, 0,
                         z ? bih1b : bih1f, z ? bhh1b : bhh1f,
                         z ? pB : pA, (rem >> 3)*64, (rem & 7)*64, 256, 1.0f,
                         nullptr, nullptr, nullptr, nullptr);
    }
    __threadfence();
    grid.sync();

    // ---- phase D: lstm layer 1 ----
    if (b < 2)
        lstm_body(smem, tid, b, 1, b ? pB : pA, b ? Whh1b : Whh1f, h0, c0, h1cat);
    __threadfence();
    grid.sync();

    // ---- phase E: A' = 2log2e*(h@W1a^T + b1), B' = 2log2e*(h@W1b^T) ----
    if (b < 128) {
        int z = b >> 6, rem = b & 63;
        gemm_tile<false>(smem, smem + 2112, tid,
                         h1cat, 256, W1, 512, z ? 256 : 0,
                         z ? nullptr : b1, nullptr,
                         z ? pB : pA, (rem >> 3)*64, (rem & 7)*64, 256, TWO_LOG2E,
                         nullptr, nullptr, nullptr, nullptr);
    }
    __threadfence();
    grid.sync();

    // ---- phase F: score, 2 tiles per block (one per 256-thread half) ----
    {
        int half = tid >> 8, t = tid & 255;
        int tile = 2*b + half;                 // 0..511
        int m0 = (tile & 31) * 16, n0 = (tile >> 5) * 32;
        float* base = smem + half*6736;
        score_tile(base, base + 4224, base + 6336, base + 6464, t,
                   pA, pB, W2, b2, S, csum, m0, n0);
    }
    __threadfence();
    grid.sync();

    // ---- phase G: softmax rows b and b+256 ----
    softmax_row(b, tid, smem, smem + 8, S, csum, out);
    __syncthreads();
    softmax_row(b + 256, tid, smem, smem + 8, S, csum, out);
}

extern "C" void kernel_launch(void* const* d_in, const int* in_sizes, int n_in,
                              void* d_out, int out_size, void* d_ws, size_t ws_size,
                              hipStream_t stream)
{
    const int*   wid  = (const int*)d_in[0];
    const int*   tgi  = (const int*)d_in[1];
    const float* wemb = (const float*)d_in[2];
    const float* temb = (const float*)d_in[3];
    const float* h0   = (const float*)d_in[4];
    const float* c0   = (const float*)d_in[5];
    const float* Wih0f=(const float*)d_in[6],  *Whh0f=(const float*)d_in[7],  *bih0f=(const float*)d_in[8],  *bhh0f=(const float*)d_in[9];
    const float* Wih0b=(const float*)d_in[10], *Whh0b=(const float*)d_in[11], *bih0b=(const float*)d_in[12], *bhh0b=(const float*)d_in[13];
    const float* Wih1f=(const float*)d_in[14], *Whh1f=(const float*)d_in[15], *bih1f=(const float*)d_in[16], *bhh1f=(const float*)d_in[17];
    const float* Wih1b=(const float*)d_in[18], *Whh1b=(const float*)d_in[19], *bih1b=(const float*)d_in[20], *bhh1b=(const float*)d_in[21];
    const float* W1   = (const float*)d_in[22];
    const float* b1   = (const float*)d_in[23];
    const float* W2   = (const float*)d_in[24];
    const float* b2   = (const float*)d_in[25];

    float* ws    = (float*)d_ws;
    float* h0cat = ws;              // [0, 131072)
    float* h1cat = ws + 131072;     // [131072, 262144)
    float* pA    = ws + 262144;     // [262144, 524288)
    float* pB    = ws + 524288;     // [524288, 786432)
    float* S     = ws;              // [0, 262144)  (h0cat/h1cat dead by score)
    float* csum  = ws + 786432;     // [786432, 786944)
    float* out   = (float*)d_out;

    void* kargs[] = {
        (void*)&wid, (void*)&tgi, (void*)&wemb, (void*)&temb,
        (void*)&h0, (void*)&c0,
        (void*)&Wih0f, (void*)&Whh0f, (void*)&bih0f, (void*)&bhh0f,
        (void*)&Wih0b, (void*)&Whh0b, (void*)&bih0b, (void*)&bhh0b,
        (void*)&Wih1f, (void*)&Whh1f, (void*)&bih1f, (void*)&bhh1f,
        (void*)&Wih1b, (void*)&Whh1b, (void*)&bih1b, (void*)&bhh1b,
        (void*)&W1, (void*)&b1, (void*)&W2, (void*)&b2,
        (void*)&h0cat, (void*)&h1cat, (void*)&pA, (void*)&pB,
        (void*)&S, (void*)&csum, (void*)&out
    };
    hipLaunchCooperativeKernel(fused, dim3(256), dim3(512), kargs, 0, stream);
}